// Round 6
// baseline (416.106 us; speedup 1.0000x reference)
//
#include <hip/hip_runtime.h>
#include <stdint.h>

// ModulatedConv2d: B=8, C=512, O=512, K=3, WDIM=512, H=W=64
// Round-11: k_conv was LDS-PORT-bound (model: 513 KB LDS traffic/iter-CU ~6000
//   cyc vs MFMA 3725 cyc; 0 conflicts = pure throughput). Fix: A-operand moved
//   from LDS to direct global->VGPR fragment loads (awT L2-hot, 16B/lane
//   contiguous), software-pipelined across kx (A[kx+1] flies under kx's 32
//   MFMAs). LDS now stages only the B halo strip (double-buffered, 33 KB,
//   one barrier/iter). XCD-bijective block remap keeps each XCD's awT panel
//   (1.18 MB) L2-resident. B staging + swizzle + epilogue = R1-verified code.

#define MOD_SCALE  0.044194173824159216f   // 1/sqrt(512)
#define CONV_SCALE 0.014731391274719739f   // 1/sqrt(4608)

typedef __attribute__((ext_vector_type(4))) float f32x4;
typedef __attribute__((ext_vector_type(8))) short bf16x8;

__device__ inline unsigned short f2bf(float f) {   // round-to-nearest-even
  uint32_t u = __float_as_uint(f);
  uint32_t r = (u + 0x7fffu + ((u >> 16) & 1u)) >> 16;
  return (unsigned short)r;
}

__device__ inline void gload_lds16(const void* g, void* l) {
  __builtin_amdgcn_global_load_lds(
      (const __attribute__((address_space(1))) void*)g,
      (__attribute__((address_space(3))) void*)l, 16, 0, 0);
}

// ---------- style: s[b][c] = w[b].modw[c]*MOD_SCALE + modb[c] + 1 ----------
__global__ __launch_bounds__(256) void k_style(const float* __restrict__ w,
                                               const float* __restrict__ modw,
                                               const float* __restrict__ modb,
                                               float* __restrict__ s_out) {
  __shared__ float red[256];
  const int tid = threadIdx.x;
  const int sb = blockIdx.x;
  const int cb = sb & 7, b = sb >> 3;
  const int cl = tid >> 2, qq = tid & 3;
  const int c = (cb << 6) + cl;
  const float4* wd = (const float4*)(w + (b << 9) + (qq << 7));
  const float4* md = (const float4*)(modw + ((size_t)c << 9) + (qq << 7));
  float acc = 0.f;
#pragma unroll
  for (int i = 0; i < 32; ++i) {
    float4 a = wd[i], m = md[i];
    acc += a.x * m.x + a.y * m.y + a.z * m.z + a.w * m.w;
  }
  red[tid] = acc;
  __syncthreads();
  if (tid < 64) {
    float v = red[tid * 4] + red[tid * 4 + 1] + red[tid * 4 + 2] + red[tid * 4 + 3];
    int cc = (cb << 6) + tid;
    s_out[(b << 9) + cc] = v * MOD_SCALE + modb[cc] + 1.0f;
  }
}

// ---------- prep: xpad[b][py][px][c] = bf16(x[b][c][py-1][px-1] * s[b][c]) ----------
__global__ __launch_bounds__(256) void k_prep(const float* __restrict__ x,
                                              const float* __restrict__ s,
                                              unsigned short* __restrict__ xp) {
  __shared__ uint32_t tb[64 * 260];   // 66,560 B
  const int blk = blockIdx.x;
  const int tid = threadIdx.x;
  if (blk < 512) {
    const int b = blk >> 6, y = blk & 63;
    const int px4 = tid & 15;          // which float4 of the 64-px row
    const int cp  = tid >> 4;          // 0..15
    const float* xb = x + (size_t)(b << 9) * 4096 + (y << 6) + (px4 << 2);
    const float* sb = s + (b << 9);
#pragma unroll
    for (int it = 0; it < 16; ++it) {
      const int cpair = cp + (it << 4);        // 0..255
      const int c0 = cpair << 1;
      const float4 a0 = *(const float4*)(xb + (size_t)c0 * 4096);
      const float4 a1 = *(const float4*)(xb + (size_t)(c0 + 1) * 4096);
      const float s0 = sb[c0], s1 = sb[c0 + 1];
      const int pxb = px4 << 2;
      tb[(pxb + 0) * 260 + cpair] = (uint32_t)f2bf(a0.x * s0) | ((uint32_t)f2bf(a1.x * s1) << 16);
      tb[(pxb + 1) * 260 + cpair] = (uint32_t)f2bf(a0.y * s0) | ((uint32_t)f2bf(a1.y * s1) << 16);
      tb[(pxb + 2) * 260 + cpair] = (uint32_t)f2bf(a0.z * s0) | ((uint32_t)f2bf(a1.z * s1) << 16);
      tb[(pxb + 3) * 260 + cpair] = (uint32_t)f2bf(a0.w * s0) | ((uint32_t)f2bf(a1.w * s1) << 16);
    }
    __syncthreads();
    const int wv = tid >> 6, l = tid & 63;
    uint32_t* xpw = (uint32_t*)xp;
#pragma unroll
    for (int it = 0; it < 16; ++it) {
      const int px = (wv << 4) + it;
      const uint4 v = *(const uint4*)(tb + px * 260 + (l << 2));  // 16B-aligned
      const size_t base = ((size_t)b * 4356 + (size_t)(y + 1) * 66 + (px + 1)) << 8;
      ((uint4*)(xpw + base))[l] = v;   // wave writes contiguous 1 KB
    }
  } else {
    // ---- zero pad border (260 segments x 8 batches) ----
    const int q = blk - 512;
    const int b = q / 260, p = q - b * 260;
    int py, px;
    if (p < 66)       { py = 0;       px = p; }
    else if (p < 132) { py = 65;      px = p - 66; }
    else if (p < 196) { py = p - 131; px = 0; }
    else              { py = p - 195; px = 65; }
    uint32_t* dst = (uint32_t*)(xp + ((size_t)b * 4356 + py * 66 + px) * 512);
    dst[tid] = 0u;
  }
}

// ---------- fused demod + weight convert: one block per o ----------
__global__ __launch_bounds__(256) void k_fwd(const float* __restrict__ bw,
                                             const float* __restrict__ s,
                                             unsigned short* __restrict__ awT,
                                             float* __restrict__ d_out) {
  __shared__ float lw[4608];   // bw row, [c][tap]
  __shared__ float ls[4096];   // s, [b][c]
  __shared__ float red[32];
  const int tid = threadIdx.x;
  const int o = blockIdx.x;
  {
    const float4* src = (const float4*)(bw + (size_t)o * 4608);
    float4* dst = (float4*)lw;
#pragma unroll
    for (int i = 0; i < 4; ++i) dst[tid + (i << 8)] = src[tid + (i << 8)];
    if (tid < 128) dst[tid + 1024] = src[tid + 1024];
  }
  {
    const float4* src = (const float4*)s;
    float4* dst = (float4*)ls;
#pragma unroll
    for (int i = 0; i < 4; ++i) dst[tid + (i << 8)] = src[tid + (i << 8)];
  }
  __syncthreads();
  const int c0 = tid << 1;
  const int base = c0 * 9;
  float wq0 = 0.f, wq1 = 0.f;
#pragma unroll
  for (int j = 0; j < 9; ++j) {
    float a = lw[base + j];      wq0 += a * a;
    float b2 = lw[base + 9 + j]; wq1 += b2 * b2;
  }
  const int lane = tid & 63, wv = tid >> 6;
#pragma unroll
  for (int b = 0; b < 8; ++b) {
    float s0 = ls[(b << 9) + c0], s1 = ls[(b << 9) + c0 + 1];
    float v = wq0 * s0 * s0 + wq1 * s1 * s1;
#pragma unroll
    for (int off = 32; off > 0; off >>= 1) v += __shfl_down(v, off, 64);
    if (lane == 0) red[(b << 2) + wv] = v;
  }
  __syncthreads();
  if (tid < 8) {
    float a = red[tid << 2] + red[(tid << 2) + 1] + red[(tid << 2) + 2] + red[(tid << 2) + 3];
    d_out[(tid << 9) + o] = rsqrtf(a * (1.0f / 4608.0f)) * CONV_SCALE;
  }
  // bf16 convert of the raw base weight (once, no per-batch loop)
  uint32_t* dst = (uint32_t*)(awT + (size_t)o * 4608);
#pragma unroll
  for (int j = 0; j < 9; ++j)
    dst[(j << 8) + tid] = (uint32_t)f2bf(lw[base + j]) |
                          ((uint32_t)f2bf(lw[base + 9 + j]) << 16);
}

// ---------- main conv: 128x128 tile, BK=64, A in registers, B in LDS ----------
// A fragments: global->VGPR (16B/lane), pipelined across kx.
// B: R1-verified halo staging + 8-chunk XOR swizzle, double-buffered (33 KB).
// One barrier per (ky,kb) iteration; 24 iterations of 96 MFMA/wave.
__global__ __launch_bounds__(256, 2) void k_conv(const unsigned short* __restrict__ awT,
                                                 const unsigned short* __restrict__ xpad,
                                                 const float* __restrict__ dmod,
                                                 float* __restrict__ out) {
  __shared__ alignas(16) unsigned short Bs[2][8448];   // 2 x 16.5 KB
  const int tid = threadIdx.x;

  // XCD-bijective remap: group g=(y, z&1) constant per XCD -> awT panel L2-resident
  const int bid = blockIdx.x;          // 0..1023
  const int g   = bid & 7;
  const int k   = bid >> 3;            // 0..127
  const int nI  = k & 31;
  const int zq  = k >> 5;              // 0..3
  const int b   = (zq << 1) | (g >> 2);
  const int m0  = (g & 3) << 7;
  const int n0  = nI << 7;
  const int y0  = n0 >> 6;

  // B staging (R1 verbatim): 8-chunk XOR-rotation swizzle
  const int srow = tid >> 3;                         // 0..31
  const int schk = ((tid & 7) - (srow & 7)) & 7;     // swizzled logical chunk
  const int scol = schk << 3;
  const size_t bx = (size_t)b * (66 * 66 * 512);

  const int lane = tid & 63;
  const int wv   = tid >> 6;
  const int moff = (wv >> 1) << 6;
  const int noff = (wv & 1) << 6;
  const int noffp = noff ? 66 : 0;
  const int lm   = lane & 15;
  const int g4   = lane >> 4;

  // B reader offsets per (kx,h): row = noffp + lm + kx (+16j)
  int boff[3][2];
#pragma unroll
  for (int kx = 0; kx < 3; ++kx) {
    const int rb = noffp + lm + kx;
#pragma unroll
    for (int h = 0; h < 2; ++h)
      boff[kx][h] = rb * 64 + ((((h << 2) + g4) + rb) & 7) * 8;
  }

  // A fragment base: lane (lm,g4) reads awT[(m0+moff+lm+16i)*4608 + col + g4*8 .. +8)
  const unsigned short* aBase = awT + (size_t)(m0 + moff + lm) * 4608 + (g4 << 3);

  f32x4 acc[4][4];
#pragma unroll
  for (int i = 0; i < 4; ++i)
#pragma unroll
    for (int j = 0; j < 4; ++j) acc[i][j] = (f32x4){0.f, 0.f, 0.f, 0.f};

  bf16x8 a0[2][4], a1[2][4], a2[2][4];

  auto stageB = [&](int buf, int it) {
    const int ky = it >> 3, kcol = (it & 7) << 6;
    const unsigned short* Bp = xpad + bx + (size_t)((y0 + ky) * 66 + srow) * 512 + scol + kcol;
#pragma unroll
    for (int gg = 0; gg < 4; ++gg)
      gload_lds16(Bp + gg * (32 * 512), &Bs[buf][((gg << 8) + tid) << 3]);
    if (tid < 32) gload_lds16(Bp + 128 * 512, &Bs[buf][8192 + tid * 8]);
  };

  auto loadA = [&](bf16x8 (&dst)[2][4], int it, int kx) {
    const int ky = it >> 3, kcol = (it & 7) << 6;
    const unsigned short* ap = aBase + ((ky * 3 + kx) << 9) + kcol;
#pragma unroll
    for (int h = 0; h < 2; ++h)
#pragma unroll
      for (int i = 0; i < 4; ++i)
        dst[h][i] = *(const bf16x8*)(ap + (h << 5) + (size_t)i * 73728);  // 16 rows
  };

  auto mfmaKX = [&](const bf16x8 (&af)[2][4], const unsigned short* Bb, const int (&bo)[2]) {
    __builtin_amdgcn_s_setprio(1);
#pragma unroll
    for (int h = 0; h < 2; ++h) {
      bf16x8 bfr[4];
      const unsigned short* pb = Bb + bo[h];
#pragma unroll
      for (int j = 0; j < 4; ++j) bfr[j] = *(const bf16x8*)(pb + (j << 10));
#pragma unroll
      for (int i = 0; i < 4; ++i)
#pragma unroll
        for (int j = 0; j < 4; ++j)
          acc[i][j] = __builtin_amdgcn_mfma_f32_16x16x32_bf16(af[h][i], bfr[j], acc[i][j], 0, 0, 0);
    }
    __builtin_amdgcn_s_setprio(0);
  };

  stageB(0, 0);
  loadA(a0, 0, 0);
  __syncthreads();   // drains vmcnt(0): Bs[0] + a0 ready

  int cur = 0;
#pragma unroll 1
  for (int it = 0; it < 23; ++it) {
    loadA(a1, it, 1);                 // flies under kx0 MFMAs
    stageB(cur ^ 1, it + 1);          // B(it+1) delivery hides under all 96 MFMAs
    mfmaKX(a0, Bs[cur], boff[0]);
    loadA(a2, it, 2);                 // flies under kx1 MFMAs
    mfmaKX(a1, Bs[cur], boff[1]);
    loadA(a0, it + 1, 0);             // next iter's kx0, flies under kx2 MFMAs
    mfmaKX(a2, Bs[cur], boff[2]);
    __syncthreads();                  // drain prefetches (already delivered) + sync
    cur ^= 1;
  }
  // peeled last iteration (no next-iter prefetch -> no conditional vmcnt merge)
  loadA(a1, 23, 1);
  mfmaKX(a0, Bs[cur], boff[0]);
  loadA(a2, 23, 2);
  mfmaKX(a1, Bs[cur], boff[1]);
  mfmaKX(a2, Bs[cur], boff[2]);

  // epilogue: D layout col=lane&15 (pixel), row=(lane>>4)*4+reg (o); apply D[b][o]
  const float* dB = dmod + (b << 9) + m0 + moff;
  float* op = out + (size_t)((b << 9) + m0 + moff) * 4096 + n0 + noff;
#pragma unroll
  for (int i = 0; i < 4; ++i) {
#pragma unroll
    for (int r = 0; r < 4; ++r) {
      const int m = i * 16 + (g4 << 2) + r;
      const float dm = dB[m];
#pragma unroll
      for (int j = 0; j < 4; ++j)
        op[(size_t)m * 4096 + (j << 4) + lm] = acc[i][j][r] * dm;
    }
  }
}

extern "C" void kernel_launch(void* const* d_in, const int* in_sizes, int n_in,
                              void* d_out, int out_size, void* d_ws, size_t ws_size,
                              hipStream_t stream) {
  const float* x    = (const float*)d_in[0];   // (8,512,64,64)
  const float* w    = (const float*)d_in[1];   // (8,512)
  const float* bw   = (const float*)d_in[2];   // (1,512,512,3,3)
  const float* modw = (const float*)d_in[3];   // (512,512)
  const float* modb = (const float*)d_in[4];   // (512,)
  float* out = (float*)d_out;                  // (8,512,64,64) fp32
  char* ws = (char*)d_ws;

  float* s_buf = (float*)(ws);                              // 16 KB
  float* d_buf = (float*)(ws + 16384);                      // 16 KB
  unsigned short* awT  = (unsigned short*)(ws + 32768);     // 4,718,592 B
  unsigned short* xpad = (unsigned short*)(ws + 4751360);   // 35,684,352 B

  (void)in_sizes; (void)n_in; (void)out_size; (void)ws_size;

  k_style<<<64,   256, 0, stream>>>(w, modw, modb, s_buf);
  k_fwd  <<<512,  256, 0, stream>>>(bw, s_buf, awT, d_buf);
  k_prep <<<2592, 256, 0, stream>>>(x, s_buf, xpad);
  k_conv <<<1024, 256, 0, stream>>>(awT, xpad, d_buf, out);
}

// Round 7
// 279.352 us; speedup vs baseline: 1.4895x; 1.4895x over previous
//
#include <hip/hip_runtime.h>
#include <stdint.h>

// ModulatedConv2d: B=8, C=512, O=512, K=3, WDIM=512, H=W=64
// Round-12: k_conv scaled to 256x256 block / 512 thr / 8 waves (2 per SIMD,
//   same as R1), wave tile 64x128 (acc[4][8]). LDS bytes per FLOP -31%
//   (the measured long pole was the LDS port: 5700 of 6830 cyc/iter in R1).
//   Same BK=64, same 24-iter stage->sync->MFMA->sync skeleton, same XOR-8
//   swizzle, bit-identical accumulation order. Grid=256 blocks = 1 per CU;
//   bid decode keeps one A-panel (2.36 MB) resident per XCD L2.

#define MOD_SCALE  0.044194173824159216f   // 1/sqrt(512)
#define CONV_SCALE 0.014731391274719739f   // 1/sqrt(4608)

typedef __attribute__((ext_vector_type(4))) float f32x4;
typedef __attribute__((ext_vector_type(8))) short bf16x8;

__device__ inline unsigned short f2bf(float f) {   // round-to-nearest-even
  uint32_t u = __float_as_uint(f);
  uint32_t r = (u + 0x7fffu + ((u >> 16) & 1u)) >> 16;
  return (unsigned short)r;
}

__device__ inline void gload_lds16(const void* g, void* l) {
  __builtin_amdgcn_global_load_lds(
      (const __attribute__((address_space(1))) void*)g,
      (__attribute__((address_space(3))) void*)l, 16, 0, 0);
}

// ---------- style: s[b][c] = w[b].modw[c]*MOD_SCALE + modb[c] + 1 ----------
__global__ __launch_bounds__(256) void k_style(const float* __restrict__ w,
                                               const float* __restrict__ modw,
                                               const float* __restrict__ modb,
                                               float* __restrict__ s_out) {
  __shared__ float red[256];
  const int tid = threadIdx.x;
  const int sb = blockIdx.x;
  const int cb = sb & 7, b = sb >> 3;
  const int cl = tid >> 2, qq = tid & 3;
  const int c = (cb << 6) + cl;
  const float4* wd = (const float4*)(w + (b << 9) + (qq << 7));
  const float4* md = (const float4*)(modw + ((size_t)c << 9) + (qq << 7));
  float acc = 0.f;
#pragma unroll
  for (int i = 0; i < 32; ++i) {
    float4 a = wd[i], m = md[i];
    acc += a.x * m.x + a.y * m.y + a.z * m.z + a.w * m.w;
  }
  red[tid] = acc;
  __syncthreads();
  if (tid < 64) {
    float v = red[tid * 4] + red[tid * 4 + 1] + red[tid * 4 + 2] + red[tid * 4 + 3];
    int cc = (cb << 6) + tid;
    s_out[(b << 9) + cc] = v * MOD_SCALE + modb[cc] + 1.0f;
  }
}

// ---------- prep: xpad[b][py][px][c] = bf16(x[b][c][py-1][px-1] * s[b][c]) ----------
__global__ __launch_bounds__(256) void k_prep(const float* __restrict__ x,
                                              const float* __restrict__ s,
                                              unsigned short* __restrict__ xp) {
  __shared__ uint32_t tb[64 * 260];   // 66,560 B
  const int blk = blockIdx.x;
  const int tid = threadIdx.x;
  if (blk < 512) {
    const int b = blk >> 6, y = blk & 63;
    const int px4 = tid & 15;          // which float4 of the 64-px row
    const int cp  = tid >> 4;          // 0..15
    const float* xb = x + (size_t)(b << 9) * 4096 + (y << 6) + (px4 << 2);
    const float* sb = s + (b << 9);
#pragma unroll
    for (int it = 0; it < 16; ++it) {
      const int cpair = cp + (it << 4);        // 0..255
      const int c0 = cpair << 1;
      const float4 a0 = *(const float4*)(xb + (size_t)c0 * 4096);
      const float4 a1 = *(const float4*)(xb + (size_t)(c0 + 1) * 4096);
      const float s0 = sb[c0], s1 = sb[c0 + 1];
      const int pxb = px4 << 2;
      tb[(pxb + 0) * 260 + cpair] = (uint32_t)f2bf(a0.x * s0) | ((uint32_t)f2bf(a1.x * s1) << 16);
      tb[(pxb + 1) * 260 + cpair] = (uint32_t)f2bf(a0.y * s0) | ((uint32_t)f2bf(a1.y * s1) << 16);
      tb[(pxb + 2) * 260 + cpair] = (uint32_t)f2bf(a0.z * s0) | ((uint32_t)f2bf(a1.z * s1) << 16);
      tb[(pxb + 3) * 260 + cpair] = (uint32_t)f2bf(a0.w * s0) | ((uint32_t)f2bf(a1.w * s1) << 16);
    }
    __syncthreads();
    const int wv = tid >> 6, l = tid & 63;
    uint32_t* xpw = (uint32_t*)xp;
#pragma unroll
    for (int it = 0; it < 16; ++it) {
      const int px = (wv << 4) + it;
      const uint4 v = *(const uint4*)(tb + px * 260 + (l << 2));  // 16B-aligned
      const size_t base = ((size_t)b * 4356 + (size_t)(y + 1) * 66 + (px + 1)) << 8;
      ((uint4*)(xpw + base))[l] = v;   // wave writes contiguous 1 KB
    }
  } else {
    // ---- zero pad border (260 segments x 8 batches) ----
    const int q = blk - 512;
    const int b = q / 260, p = q - b * 260;
    int py, px;
    if (p < 66)       { py = 0;       px = p; }
    else if (p < 132) { py = 65;      px = p - 66; }
    else if (p < 196) { py = p - 131; px = 0; }
    else              { py = p - 195; px = 65; }
    uint32_t* dst = (uint32_t*)(xp + ((size_t)b * 4356 + py * 66 + px) * 512);
    dst[tid] = 0u;
  }
}

// ---------- fused demod + weight convert: one block per o ----------
__global__ __launch_bounds__(256) void k_fwd(const float* __restrict__ bw,
                                             const float* __restrict__ s,
                                             unsigned short* __restrict__ awT,
                                             float* __restrict__ d_out) {
  __shared__ float lw[4608];   // bw row, [c][tap]
  __shared__ float ls[4096];   // s, [b][c]
  __shared__ float red[32];
  const int tid = threadIdx.x;
  const int o = blockIdx.x;
  {
    const float4* src = (const float4*)(bw + (size_t)o * 4608);
    float4* dst = (float4*)lw;
#pragma unroll
    for (int i = 0; i < 4; ++i) dst[tid + (i << 8)] = src[tid + (i << 8)];
    if (tid < 128) dst[tid + 1024] = src[tid + 1024];
  }
  {
    const float4* src = (const float4*)s;
    float4* dst = (float4*)ls;
#pragma unroll
    for (int i = 0; i < 4; ++i) dst[tid + (i << 8)] = src[tid + (i << 8)];
  }
  __syncthreads();
  const int c0 = tid << 1;
  const int base = c0 * 9;
  float wq0 = 0.f, wq1 = 0.f;
#pragma unroll
  for (int j = 0; j < 9; ++j) {
    float a = lw[base + j];      wq0 += a * a;
    float b2 = lw[base + 9 + j]; wq1 += b2 * b2;
  }
  const int lane = tid & 63, wv = tid >> 6;
#pragma unroll
  for (int b = 0; b < 8; ++b) {
    float s0 = ls[(b << 9) + c0], s1 = ls[(b << 9) + c0 + 1];
    float v = wq0 * s0 * s0 + wq1 * s1 * s1;
#pragma unroll
    for (int off = 32; off > 0; off >>= 1) v += __shfl_down(v, off, 64);
    if (lane == 0) red[(b << 2) + wv] = v;
  }
  __syncthreads();
  if (tid < 8) {
    float a = red[tid << 2] + red[(tid << 2) + 1] + red[(tid << 2) + 2] + red[(tid << 2) + 3];
    d_out[(tid << 9) + o] = rsqrtf(a * (1.0f / 4608.0f)) * CONV_SCALE;
  }
  // bf16 convert of the raw base weight (once, no per-batch loop)
  uint32_t* dst = (uint32_t*)(awT + (size_t)o * 4608);
#pragma unroll
  for (int j = 0; j < 9; ++j)
    dst[(j << 8) + tid] = (uint32_t)f2bf(lw[base + j]) |
                          ((uint32_t)f2bf(lw[base + 9 + j]) << 16);
}

// ---------- main conv: 256x256 block, 512 thr, BK=64, wave tile 64x128 ----------
// LDS: As 3 tap-panels 256x64 (96 KB) + Bs 264-px halo strip x 64 (33 KB).
// 8-chunk XOR-rotation swizzle (R1-verified): logical chunk c of row r at
// phys (c+r)&7; staging thread t fetches logical ((t&7)-((t>>3)&7))&7.
__global__ __launch_bounds__(512, 2) void k_conv(const unsigned short* __restrict__ awT,
                                                 const unsigned short* __restrict__ xpad,
                                                 const float* __restrict__ dmod,
                                                 float* __restrict__ out) {
  __shared__ alignas(16) unsigned short As[3 * 16384];  // 96 KB
  __shared__ alignas(16) unsigned short Bs[16896];      // 33 KB
  const int tid = threadIdx.x;

  // bid decode: bm varies fastest -> XCD (bid&7) sees one m-panel, two b's
  const int bid = blockIdx.x;          // 0..255
  const int bm  = bid & 15;            // b*2 + mblk
  const int nI  = bid >> 4;            // 0..15
  const int b   = bm >> 1;
  const int m0  = (bm & 1) << 8;       // 0 or 256
  const int n0  = nI << 8;             // 256-px tile
  const int y0  = n0 >> 6;             // 4 output rows per tile

  // staging mapping (512 threads): row = g*64 + (t>>3), phys chunk t&7
  const int srow = tid >> 3;                         // 0..63
  const int schk = ((tid & 7) - (srow & 7)) & 7;     // swizzled logical chunk
  const int scol = schk << 3;

  const unsigned short* A0 = awT + (size_t)(m0 + srow) * 4608 + scol;
  const size_t bx = (size_t)b * (66 * 66 * 512);
  const unsigned short* B0 = xpad + bx + (size_t)(y0 * 66 + srow) * 512 + scol;

  const int lane = tid & 63;
  const int wv   = tid >> 6;           // 0..7
  const int moff = (wv >> 1) << 6;     // 0,64,128,192
  const int noff = (wv & 1) << 7;      // 0 or 128
  const int lm   = lane & 15;
  const int g4   = lane >> 4;

  // A reader offsets (ushort index within a 16384-ushort panel)
  const int arow = moff + lm;
  int aoff[2];
#pragma unroll
  for (int h = 0; h < 2; ++h)
    aoff[h] = arow * 64 + ((((h << 2) + g4) + arow) & 7) * 8;
  // B reader offsets: strip px = (wv&1)*132 + jr*66 + (j&3)*16 + lm + kx
  int boff[3][2][2];   // [kx][jr][h]
#pragma unroll
  for (int kx = 0; kx < 3; ++kx)
#pragma unroll
    for (int jr = 0; jr < 2; ++jr) {
      const int rb = (wv & 1) * 132 + jr * 66 + lm + kx;
#pragma unroll
      for (int h = 0; h < 2; ++h)
        boff[kx][jr][h] = rb * 64 + ((((h << 2) + g4) + rb) & 7) * 8;
    }

  f32x4 acc[4][8];
#pragma unroll
  for (int i = 0; i < 4; ++i)
#pragma unroll
    for (int j = 0; j < 8; ++j) acc[i][j] = (f32x4){0.f, 0.f, 0.f, 0.f};

#pragma unroll 1
  for (int ky = 0; ky < 3; ++ky) {
#pragma unroll 1
    for (int kb = 0; kb < 8; ++kb) {
      const int kcol = kb << 6;
      // stage 3 A tap-panels: 4 passes of 64 rows each
#pragma unroll
      for (int kx = 0; kx < 3; ++kx) {
        const unsigned short* Ap = A0 + ((ky * 3 + kx) << 9) + kcol;
#pragma unroll
        for (int g = 0; g < 4; ++g)
          gload_lds16(Ap + (size_t)(g << 6) * 4608,
                      As + (kx << 14) + (g << 12) + (tid << 3));
      }
      // stage B halo strip: 264 px (4 passes of 64 + 8-px remainder)
      const unsigned short* Bp = B0 + (size_t)(ky * 66) * 512 + kcol;
#pragma unroll
      for (int g = 0; g < 4; ++g)
        gload_lds16(Bp + (size_t)(g << 6) * 512, Bs + (g << 12) + (tid << 3));
      if (tid < 64) gload_lds16(Bp + (size_t)256 * 512, Bs + 16384 + (tid << 3));
      __syncthreads();
      __builtin_amdgcn_s_setprio(1);
#pragma unroll
      for (int kx = 0; kx < 3; ++kx) {
#pragma unroll
        for (int h = 0; h < 2; ++h) {
          bf16x8 af[4], bfr[8];
          const unsigned short* pa = As + (kx << 14) + aoff[h];
#pragma unroll
          for (int i = 0; i < 4; ++i) af[i] = *(const bf16x8*)(pa + (i << 10));
#pragma unroll
          for (int j = 0; j < 8; ++j)
            bfr[j] = *(const bf16x8*)(Bs + boff[kx][j >> 2][h] + ((j & 3) << 10));
#pragma unroll
          for (int i = 0; i < 4; ++i)
#pragma unroll
            for (int j = 0; j < 8; ++j)
              acc[i][j] = __builtin_amdgcn_mfma_f32_16x16x32_bf16(af[i], bfr[j], acc[i][j], 0, 0, 0);
        }
      }
      __builtin_amdgcn_s_setprio(0);
      __syncthreads();
    }
  }

  // epilogue: D layout col=lane&15 (pixel), row=(lane>>4)*4+reg (o); apply D[b][o]
  const float* dB = dmod + (b << 9) + m0 + moff;
  float* op = out + (size_t)((b << 9) + m0 + moff) * 4096 + n0 + noff;
#pragma unroll
  for (int i = 0; i < 4; ++i) {
#pragma unroll
    for (int r = 0; r < 4; ++r) {
      const int m = i * 16 + (g4 << 2) + r;
      const float dm = dB[m];
#pragma unroll
      for (int j = 0; j < 8; ++j)
        op[(size_t)m * 4096 + (j << 4) + lm] = acc[i][j][r] * dm;
    }
  }
}

extern "C" void kernel_launch(void* const* d_in, const int* in_sizes, int n_in,
                              void* d_out, int out_size, void* d_ws, size_t ws_size,
                              hipStream_t stream) {
  const float* x    = (const float*)d_in[0];   // (8,512,64,64)
  const float* w    = (const float*)d_in[1];   // (8,512)
  const float* bw   = (const float*)d_in[2];   // (1,512,512,3,3)
  const float* modw = (const float*)d_in[3];   // (512,512)
  const float* modb = (const float*)d_in[4];   // (512,)
  float* out = (float*)d_out;                  // (8,512,64,64) fp32
  char* ws = (char*)d_ws;

  float* s_buf = (float*)(ws);                              // 16 KB
  float* d_buf = (float*)(ws + 16384);                      // 16 KB
  unsigned short* awT  = (unsigned short*)(ws + 32768);     // 4,718,592 B
  unsigned short* xpad = (unsigned short*)(ws + 4751360);   // 35,684,352 B

  (void)in_sizes; (void)n_in; (void)out_size; (void)ws_size;

  k_style<<<64,   256, 0, stream>>>(w, modw, modb, s_buf);
  k_fwd  <<<512,  256, 0, stream>>>(bw, s_buf, awT, d_buf);
  k_prep <<<2592, 256, 0, stream>>>(x, s_buf, xpad);
  k_conv <<<256,  512, 0, stream>>>(awT, xpad, d_buf, out);
}

// Round 9
// 269.846 us; speedup vs baseline: 1.5420x; 1.0352x over previous
//
#include <hip/hip_runtime.h>
#include <stdint.h>

// ModulatedConv2d: B=8, C=512, O=512, K=3, WDIM=512, H=W=64
// Round-13 (resubmit after infra failure): k_conv = R4's verified BK=32
//   structure with wave tile widened to 64x128 (block 128x256, 4 waves,
//   acc[4][8]). LDS reads/MFMA 0.5->0.375, staged bytes/iter -37%, while
//   KEEPING the R1-proven 2-blocks/CU interleave (LDS 40.5 KB/block) and
//   identical per-CU barrier cadence (2x48 == 4x24). Calibrated poles per
//   2-block window: MFMA 3725 cyc vs LDS ~3360 (was 4660). XCD decode pins
//   one 1.18 MB A-panel per XCD L2.

#define MOD_SCALE  0.044194173824159216f   // 1/sqrt(512)
#define CONV_SCALE 0.014731391274719739f   // 1/sqrt(4608)

typedef __attribute__((ext_vector_type(4))) float f32x4;
typedef __attribute__((ext_vector_type(8))) short bf16x8;

__device__ inline unsigned short f2bf(float f) {   // round-to-nearest-even
  uint32_t u = __float_as_uint(f);
  uint32_t r = (u + 0x7fffu + ((u >> 16) & 1u)) >> 16;
  return (unsigned short)r;
}

__device__ inline void gload_lds16(const void* g, void* l) {
  __builtin_amdgcn_global_load_lds(
      (const __attribute__((address_space(1))) void*)g,
      (__attribute__((address_space(3))) void*)l, 16, 0, 0);
}

// ---------- style: s[b][c] = w[b].modw[c]*MOD_SCALE + modb[c] + 1 ----------
__global__ __launch_bounds__(256) void k_style(const float* __restrict__ w,
                                               const float* __restrict__ modw,
                                               const float* __restrict__ modb,
                                               float* __restrict__ s_out) {
  __shared__ float red[256];
  const int tid = threadIdx.x;
  const int sb = blockIdx.x;
  const int cb = sb & 7, b = sb >> 3;
  const int cl = tid >> 2, qq = tid & 3;
  const int c = (cb << 6) + cl;
  const float4* wd = (const float4*)(w + (b << 9) + (qq << 7));
  const float4* md = (const float4*)(modw + ((size_t)c << 9) + (qq << 7));
  float acc = 0.f;
#pragma unroll
  for (int i = 0; i < 32; ++i) {
    float4 a = wd[i], m = md[i];
    acc += a.x * m.x + a.y * m.y + a.z * m.z + a.w * m.w;
  }
  red[tid] = acc;
  __syncthreads();
  if (tid < 64) {
    float v = red[tid * 4] + red[tid * 4 + 1] + red[tid * 4 + 2] + red[tid * 4 + 3];
    int cc = (cb << 6) + tid;
    s_out[(b << 9) + cc] = v * MOD_SCALE + modb[cc] + 1.0f;
  }
}

// ---------- prep: xpad[b][py][px][c] = bf16(x[b][c][py-1][px-1] * s[b][c]) ----------
__global__ __launch_bounds__(256) void k_prep(const float* __restrict__ x,
                                              const float* __restrict__ s,
                                              unsigned short* __restrict__ xp) {
  __shared__ uint32_t tb[64 * 260];   // 66,560 B
  const int blk = blockIdx.x;
  const int tid = threadIdx.x;
  if (blk < 512) {
    const int b = blk >> 6, y = blk & 63;
    const int px4 = tid & 15;          // which float4 of the 64-px row
    const int cp  = tid >> 4;          // 0..15
    const float* xb = x + (size_t)(b << 9) * 4096 + (y << 6) + (px4 << 2);
    const float* sb = s + (b << 9);
#pragma unroll
    for (int it = 0; it < 16; ++it) {
      const int cpair = cp + (it << 4);        // 0..255
      const int c0 = cpair << 1;
      const float4 a0 = *(const float4*)(xb + (size_t)c0 * 4096);
      const float4 a1 = *(const float4*)(xb + (size_t)(c0 + 1) * 4096);
      const float s0 = sb[c0], s1 = sb[c0 + 1];
      const int pxb = px4 << 2;
      tb[(pxb + 0) * 260 + cpair] = (uint32_t)f2bf(a0.x * s0) | ((uint32_t)f2bf(a1.x * s1) << 16);
      tb[(pxb + 1) * 260 + cpair] = (uint32_t)f2bf(a0.y * s0) | ((uint32_t)f2bf(a1.y * s1) << 16);
      tb[(pxb + 2) * 260 + cpair] = (uint32_t)f2bf(a0.z * s0) | ((uint32_t)f2bf(a1.z * s1) << 16);
      tb[(pxb + 3) * 260 + cpair] = (uint32_t)f2bf(a0.w * s0) | ((uint32_t)f2bf(a1.w * s1) << 16);
    }
    __syncthreads();
    const int wv = tid >> 6, l = tid & 63;
    uint32_t* xpw = (uint32_t*)xp;
#pragma unroll
    for (int it = 0; it < 16; ++it) {
      const int px = (wv << 4) + it;
      const uint4 v = *(const uint4*)(tb + px * 260 + (l << 2));  // 16B-aligned
      const size_t base = ((size_t)b * 4356 + (size_t)(y + 1) * 66 + (px + 1)) << 8;
      ((uint4*)(xpw + base))[l] = v;   // wave writes contiguous 1 KB
    }
  } else {
    // ---- zero pad border (260 segments x 8 batches) ----
    const int q = blk - 512;
    const int b = q / 260, p = q - b * 260;
    int py, px;
    if (p < 66)       { py = 0;       px = p; }
    else if (p < 132) { py = 65;      px = p - 66; }
    else if (p < 196) { py = p - 131; px = 0; }
    else              { py = p - 195; px = 65; }
    uint32_t* dst = (uint32_t*)(xp + ((size_t)b * 4356 + py * 66 + px) * 512);
    dst[tid] = 0u;
  }
}

// ---------- fused demod + weight convert: one block per o ----------
__global__ __launch_bounds__(256) void k_fwd(const float* __restrict__ bw,
                                             const float* __restrict__ s,
                                             unsigned short* __restrict__ awT,
                                             float* __restrict__ d_out) {
  __shared__ float lw[4608];   // bw row, [c][tap]
  __shared__ float ls[4096];   // s, [b][c]
  __shared__ float red[32];
  const int tid = threadIdx.x;
  const int o = blockIdx.x;
  {
    const float4* src = (const float4*)(bw + (size_t)o * 4608);
    float4* dst = (float4*)lw;
#pragma unroll
    for (int i = 0; i < 4; ++i) dst[tid + (i << 8)] = src[tid + (i << 8)];
    if (tid < 128) dst[tid + 1024] = src[tid + 1024];
  }
  {
    const float4* src = (const float4*)s;
    float4* dst = (float4*)ls;
#pragma unroll
    for (int i = 0; i < 4; ++i) dst[tid + (i << 8)] = src[tid + (i << 8)];
  }
  __syncthreads();
  const int c0 = tid << 1;
  const int base = c0 * 9;
  float wq0 = 0.f, wq1 = 0.f;
#pragma unroll
  for (int j = 0; j < 9; ++j) {
    float a = lw[base + j];      wq0 += a * a;
    float b2 = lw[base + 9 + j]; wq1 += b2 * b2;
  }
  const int lane = tid & 63, wv = tid >> 6;
#pragma unroll
  for (int b = 0; b < 8; ++b) {
    float s0 = ls[(b << 9) + c0], s1 = ls[(b << 9) + c0 + 1];
    float v = wq0 * s0 * s0 + wq1 * s1 * s1;
#pragma unroll
    for (int off = 32; off > 0; off >>= 1) v += __shfl_down(v, off, 64);
    if (lane == 0) red[(b << 2) + wv] = v;
  }
  __syncthreads();
  if (tid < 8) {
    float a = red[tid << 2] + red[(tid << 2) + 1] + red[(tid << 2) + 2] + red[(tid << 2) + 3];
    d_out[(tid << 9) + o] = rsqrtf(a * (1.0f / 4608.0f)) * CONV_SCALE;
  }
  // bf16 convert of the raw base weight (once, no per-batch loop)
  uint32_t* dst = (uint32_t*)(awT + (size_t)o * 4608);
#pragma unroll
  for (int j = 0; j < 9; ++j)
    dst[(j << 8) + tid] = (uint32_t)f2bf(lw[base + j]) |
                          ((uint32_t)f2bf(lw[base + 9 + j]) << 16);
}

// ---------- main conv: 128x256 block, 256 thr, BK=32, wave tile 64x128 ----------
// LDS: As 3 tap-panels 128x32 (24 KB) + Bs 264-px halo strip x 32 (16.5 KB).
// 4-chunk swizzle (R4-verified): phys = (logical + (row>>1)) & 3;
// staging thread t: row = g*64 + (t>>2), phys chunk t&3, logical ((t&3)-(t>>3))&3.
__global__ __launch_bounds__(256, 2) void k_conv(const unsigned short* __restrict__ awT,
                                                 const unsigned short* __restrict__ xpad,
                                                 const float* __restrict__ dmod,
                                                 float* __restrict__ out) {
  __shared__ alignas(16) unsigned short As[3 * 4096];  // 24 KB
  __shared__ alignas(16) unsigned short Bs[8448];      // 16.5 KB
  const int tid = threadIdx.x;

  // XCD decode: g=bid&7 fixes (m0, b-parity) per XCD -> A panel L2-resident
  const int bid = blockIdx.x;          // 0..511
  const int g   = bid & 7;
  const int k   = bid >> 3;            // 0..63
  const int nI  = k & 15;              // 0..15
  const int zq  = k >> 4;              // 0..3
  const int b   = (zq << 1) | (g >> 2);
  const int m0  = (g & 3) << 7;
  const int n0  = nI << 8;             // 256-px tile
  const int y0  = nI << 2;             // 4 output rows

  const int srow4 = tid >> 2;                       // 0..63
  const int sl    = ((tid & 3) - (tid >> 3)) & 3;   // logical chunk to fetch
  const int scol  = sl << 3;

  const unsigned short* A0 = awT + (size_t)(m0 + srow4) * 4608 + scol;
  const size_t bx = (size_t)b * (66 * 66 * 512);
  const unsigned short* B0 = xpad + bx + (size_t)(y0 * 66 + srow4) * 512 + scol;

  const int lane = tid & 63;
  const int wv   = tid >> 6;           // 0..3
  const int moff = (wv >> 1) << 6;     // 0 or 64
  const int noff2 = (wv & 1) << 1;     // strip-row block: 0 or 2
  const int lm   = lane & 15;
  const int g4   = lane >> 4;

  // A reader offset: row = moff+lm (+16i, swizzle-invariant)
  const int arow = moff + lm;
  const int aoff = arow * 32 + (((g4 + (arow >> 1)) & 3) << 3);
  // B reader offsets [kx][jc2]: row = (noff2+jc2)*66 + lm + kx (+16 per j&3)
  int boff[3][2];
#pragma unroll
  for (int kx = 0; kx < 3; ++kx)
#pragma unroll
    for (int jc = 0; jc < 2; ++jc) {
      const int rb = (noff2 + jc) * 66 + lm + kx;
      boff[kx][jc] = rb * 32 + (((g4 + (rb >> 1)) & 3) << 3);
    }

  f32x4 acc[4][8];
#pragma unroll
  for (int i = 0; i < 4; ++i)
#pragma unroll
    for (int j = 0; j < 8; ++j) acc[i][j] = (f32x4){0.f, 0.f, 0.f, 0.f};

#pragma unroll 1
  for (int ky = 0; ky < 3; ++ky) {
#pragma unroll 1
    for (int kb = 0; kb < 16; ++kb) {
      const int kcol = kb << 5;
      // stage 3 A tap-panels (2 passes of 64 rows each)
#pragma unroll
      for (int kx = 0; kx < 3; ++kx) {
        const unsigned short* Ap = A0 + ((ky * 3 + kx) << 9) + kcol;
#pragma unroll
        for (int g2 = 0; g2 < 2; ++g2)
          gload_lds16(Ap + (size_t)(g2 << 6) * 4608,
                      As + (kx << 12) + (((g2 << 8) + tid) << 3));
      }
      // stage B halo strip: 264 rows x 32 k (4 passes + 8-row remainder)
      const unsigned short* Bp = B0 + (size_t)(ky * 66) * 512 + kcol;
#pragma unroll
      for (int g2 = 0; g2 < 4; ++g2)
        gload_lds16(Bp + (size_t)(g2 << 6) * 512, Bs + (((g2 << 8) + tid) << 3));
      if (tid < 32) gload_lds16(Bp + (size_t)256 * 512, Bs + ((1024 + tid) << 3));
      __syncthreads();
      __builtin_amdgcn_s_setprio(1);
#pragma unroll
      for (int kx = 0; kx < 3; ++kx) {
        bf16x8 af[4], bfr[8];
        const unsigned short* pa = As + (kx << 12) + aoff;
#pragma unroll
        for (int i = 0; i < 4; ++i) af[i] = *(const bf16x8*)(pa + (i << 9));
        const unsigned short* pb0 = Bs + boff[kx][0];
        const unsigned short* pb1 = Bs + boff[kx][1];
#pragma unroll
        for (int j = 0; j < 4; ++j) {
          bfr[j]     = *(const bf16x8*)(pb0 + (j << 9));
          bfr[4 + j] = *(const bf16x8*)(pb1 + (j << 9));
        }
#pragma unroll
        for (int i = 0; i < 4; ++i)
#pragma unroll
          for (int j = 0; j < 8; ++j)
            acc[i][j] = __builtin_amdgcn_mfma_f32_16x16x32_bf16(af[i], bfr[j], acc[i][j], 0, 0, 0);
      }
      __builtin_amdgcn_s_setprio(0);
      __syncthreads();
    }
  }

  // epilogue: D layout col=lane&15 (pixel), row=(lane>>4)*4+reg (o); apply D[b][o]
  const float* dB = dmod + (b << 9) + m0 + moff;
  float* op = out + (size_t)((b << 9) + m0 + moff) * 4096 + n0 + ((wv & 1) << 7);
#pragma unroll
  for (int i = 0; i < 4; ++i) {
#pragma unroll
    for (int r = 0; r < 4; ++r) {
      const int m = i * 16 + (g4 << 2) + r;
      const float dm = dB[m];
#pragma unroll
      for (int j = 0; j < 8; ++j)
        op[(size_t)m * 4096 + (j << 4) + lm] = acc[i][j][r] * dm;
    }
  }
}

extern "C" void kernel_launch(void* const* d_in, const int* in_sizes, int n_in,
                              void* d_out, int out_size, void* d_ws, size_t ws_size,
                              hipStream_t stream) {
  const float* x    = (const float*)d_in[0];   // (8,512,64,64)
  const float* w    = (const float*)d_in[1];   // (8,512)
  const float* bw   = (const float*)d_in[2];   // (1,512,512,3,3)
  const float* modw = (const float*)d_in[3];   // (512,512)
  const float* modb = (const float*)d_in[4];   // (512,)
  float* out = (float*)d_out;                  // (8,512,64,64) fp32
  char* ws = (char*)d_ws;

  float* s_buf = (float*)(ws);                              // 16 KB
  float* d_buf = (float*)(ws + 16384);                      // 16 KB
  unsigned short* awT  = (unsigned short*)(ws + 32768);     // 4,718,592 B
  unsigned short* xpad = (unsigned short*)(ws + 4751360);   // 35,684,352 B

  (void)in_sizes; (void)n_in; (void)out_size; (void)ws_size;

  k_style<<<64,   256, 0, stream>>>(w, modw, modb, s_buf);
  k_fwd  <<<512,  256, 0, stream>>>(bw, s_buf, awT, d_buf);
  k_prep <<<2592, 256, 0, stream>>>(x, s_buf, xpad);
  k_conv <<<512,  256, 0, stream>>>(awT, xpad, d_buf, out);
}

// Round 10
// 266.335 us; speedup vs baseline: 1.5623x; 1.0132x over previous
//
#include <hip/hip_runtime.h>
#include <stdint.h>

// ModulatedConv2d: B=8, C=512, O=512, K=3, WDIM=512, H=W=64
// Round-14: k_conv = exact R1 structure (proven 136.6 us, natural dispatch
//   keeps one n-column family per XCD -> 82 MB FETCH). k_fwd + k_prep merged
//   into ONE launch (k_mid, 3104 blocks, 3-way branch): they are mutually
//   independent (both consume only s_buf), so merging removes one kernel
//   dependency edge and overlaps fwd under prep. Chain: k_style->k_mid->k_conv.

#define MOD_SCALE  0.044194173824159216f   // 1/sqrt(512)
#define CONV_SCALE 0.014731391274719739f   // 1/sqrt(4608)

typedef __attribute__((ext_vector_type(4))) float f32x4;
typedef __attribute__((ext_vector_type(8))) short bf16x8;

__device__ inline unsigned short f2bf(float f) {   // round-to-nearest-even
  uint32_t u = __float_as_uint(f);
  uint32_t r = (u + 0x7fffu + ((u >> 16) & 1u)) >> 16;
  return (unsigned short)r;
}

__device__ inline void gload_lds16(const void* g, void* l) {
  __builtin_amdgcn_global_load_lds(
      (const __attribute__((address_space(1))) void*)g,
      (__attribute__((address_space(3))) void*)l, 16, 0, 0);
}

// ---------- style: s[b][c] = w[b].modw[c]*MOD_SCALE + modb[c] + 1 ----------
__global__ __launch_bounds__(256) void k_style(const float* __restrict__ w,
                                               const float* __restrict__ modw,
                                               const float* __restrict__ modb,
                                               float* __restrict__ s_out) {
  __shared__ float red[256];
  const int tid = threadIdx.x;
  const int sb = blockIdx.x;
  const int cb = sb & 7, b = sb >> 3;
  const int cl = tid >> 2, qq = tid & 3;
  const int c = (cb << 6) + cl;
  const float4* wd = (const float4*)(w + (b << 9) + (qq << 7));
  const float4* md = (const float4*)(modw + ((size_t)c << 9) + (qq << 7));
  float acc = 0.f;
#pragma unroll
  for (int i = 0; i < 32; ++i) {
    float4 a = wd[i], m = md[i];
    acc += a.x * m.x + a.y * m.y + a.z * m.z + a.w * m.w;
  }
  red[tid] = acc;
  __syncthreads();
  if (tid < 64) {
    float v = red[tid * 4] + red[tid * 4 + 1] + red[tid * 4 + 2] + red[tid * 4 + 3];
    int cc = (cb << 6) + tid;
    s_out[(b << 9) + cc] = v * MOD_SCALE + modb[cc] + 1.0f;
  }
}

// ---------- merged mid-stage: fwd (blk<512) | xpose (<1024) | border (<3104) ----
// fwd: demod D[b][o] + bf16 weight convert (was k_fwd, verbatim).
// xpose: xpad[b][py][px][c] = bf16(x[b][c][py-1][px-1] * s[b][c]) (was k_prep).
// border: zero 1-px frame.
__global__ __launch_bounds__(256) void k_mid(const float* __restrict__ bw,
                                             const float* __restrict__ s,
                                             unsigned short* __restrict__ awT,
                                             float* __restrict__ d_out,
                                             const float* __restrict__ x,
                                             unsigned short* __restrict__ xp) {
  __shared__ uint32_t tb[64 * 260];   // 66,560 B (fwd branch reuses as floats)
  const int blk = blockIdx.x;
  const int tid = threadIdx.x;

  if (blk < 512) {
    // ---------------- fwd: one block per o ----------------
    float* lw  = (float*)tb;          // 4608 floats
    float* ls  = lw + 4608;           // 4096 floats
    float* red = ls + 4096;           // 32 floats  (total 34,944 B < 66,560)
    const int o = blk;
    {
      const float4* src = (const float4*)(bw + (size_t)o * 4608);
      float4* dst = (float4*)lw;
#pragma unroll
      for (int i = 0; i < 4; ++i) dst[tid + (i << 8)] = src[tid + (i << 8)];
      if (tid < 128) dst[tid + 1024] = src[tid + 1024];
    }
    {
      const float4* src = (const float4*)s;
      float4* dst = (float4*)ls;
#pragma unroll
      for (int i = 0; i < 4; ++i) dst[tid + (i << 8)] = src[tid + (i << 8)];
    }
    __syncthreads();
    const int c0 = tid << 1;
    const int base = c0 * 9;
    float wq0 = 0.f, wq1 = 0.f;
#pragma unroll
    for (int j = 0; j < 9; ++j) {
      float a = lw[base + j];      wq0 += a * a;
      float b2 = lw[base + 9 + j]; wq1 += b2 * b2;
    }
    const int lane = tid & 63, wv = tid >> 6;
#pragma unroll
    for (int b = 0; b < 8; ++b) {
      float s0 = ls[(b << 9) + c0], s1 = ls[(b << 9) + c0 + 1];
      float v = wq0 * s0 * s0 + wq1 * s1 * s1;
#pragma unroll
      for (int off = 32; off > 0; off >>= 1) v += __shfl_down(v, off, 64);
      if (lane == 0) red[(b << 2) + wv] = v;
    }
    __syncthreads();
    if (tid < 8) {
      float a = red[tid << 2] + red[(tid << 2) + 1] + red[(tid << 2) + 2] + red[(tid << 2) + 3];
      d_out[(tid << 9) + o] = rsqrtf(a * (1.0f / 4608.0f)) * CONV_SCALE;
    }
    uint32_t* dst = (uint32_t*)(awT + (size_t)o * 4608);
#pragma unroll
    for (int j = 0; j < 9; ++j)
      dst[(j << 8) + tid] = (uint32_t)f2bf(lw[base + j]) |
                            ((uint32_t)f2bf(lw[base + 9 + j]) << 16);
  } else if (blk < 1024) {
    // ---------------- xpose: one block per (b, y) ----------------
    const int q = blk - 512;
    const int b = q >> 6, y = q & 63;
    const int px4 = tid & 15;          // which float4 of the 64-px row
    const int cp  = tid >> 4;          // 0..15
    const float* xb = x + (size_t)(b << 9) * 4096 + (y << 6) + (px4 << 2);
    const float* sb = s + (b << 9);
#pragma unroll
    for (int it = 0; it < 16; ++it) {
      const int cpair = cp + (it << 4);        // 0..255
      const int c0 = cpair << 1;
      const float4 a0 = *(const float4*)(xb + (size_t)c0 * 4096);
      const float4 a1 = *(const float4*)(xb + (size_t)(c0 + 1) * 4096);
      const float s0 = sb[c0], s1 = sb[c0 + 1];
      const int pxb = px4 << 2;
      tb[(pxb + 0) * 260 + cpair] = (uint32_t)f2bf(a0.x * s0) | ((uint32_t)f2bf(a1.x * s1) << 16);
      tb[(pxb + 1) * 260 + cpair] = (uint32_t)f2bf(a0.y * s0) | ((uint32_t)f2bf(a1.y * s1) << 16);
      tb[(pxb + 2) * 260 + cpair] = (uint32_t)f2bf(a0.z * s0) | ((uint32_t)f2bf(a1.z * s1) << 16);
      tb[(pxb + 3) * 260 + cpair] = (uint32_t)f2bf(a0.w * s0) | ((uint32_t)f2bf(a1.w * s1) << 16);
    }
    __syncthreads();
    const int wv = tid >> 6, l = tid & 63;
    uint32_t* xpw = (uint32_t*)xp;
#pragma unroll
    for (int it = 0; it < 16; ++it) {
      const int px = (wv << 4) + it;
      const uint4 v = *(const uint4*)(tb + px * 260 + (l << 2));  // 16B-aligned
      const size_t base = ((size_t)b * 4356 + (size_t)(y + 1) * 66 + (px + 1)) << 8;
      ((uint4*)(xpw + base))[l] = v;   // wave writes contiguous 1 KB
    }
  } else {
    // ---------------- border: zero the 1-px frame ----------------
    const int q = blk - 1024;
    const int b = q / 260, p = q - b * 260;
    int py, px;
    if (p < 66)       { py = 0;       px = p; }
    else if (p < 132) { py = 65;      px = p - 66; }
    else if (p < 196) { py = p - 131; px = 0; }
    else              { py = p - 195; px = 65; }
    uint32_t* dst = (uint32_t*)(xp + ((size_t)b * 4356 + py * 66 + px) * 512);
    dst[tid] = 0u;
  }
}

// ---------- main conv: 128x128 tile, BK=64, B-halo shared across kx taps ----------
// R1-verified structure: single buffer, 66 KB LDS, 2 blocks/CU, grid (32,4,8)
// (natural dispatch: XCD = nI mod 8 -> per-XCD B-column ownership, 82 MB FETCH).
__global__ __launch_bounds__(256, 2) void k_conv(const unsigned short* __restrict__ awT,
                                                 const unsigned short* __restrict__ xpad,
                                                 const float* __restrict__ dmod,
                                                 float* __restrict__ out) {
  __shared__ alignas(16) unsigned short As[3 * 8192];  // 48 KB
  __shared__ alignas(16) unsigned short Bs[8448];      // 16.5 KB
  const int tid = threadIdx.x;
  const int b  = blockIdx.z;
  const int m0 = blockIdx.y << 7;
  const int n0 = blockIdx.x << 7;
  const int y0 = n0 >> 6;

  const int srow = tid >> 3;                         // 0..31
  const int schk = ((tid & 7) - (srow & 7)) & 7;     // swizzled logical chunk
  const int scol = schk << 3;

  const unsigned short* A0 = awT + (size_t)(m0 + srow) * 4608 + scol;
  const size_t bx = (size_t)b * (66 * 66 * 512);

  const int lane = tid & 63;
  const int wv   = tid >> 6;
  const int moff = (wv >> 1) << 6;
  const int noff = (wv & 1) << 6;
  const int noffp = noff ? 66 : 0;   // halo-strip row base for this wave
  const int lm   = lane & 15;
  const int g4   = lane >> 4;

  // A reader bases (chunk const across i since 16i = 0 mod 8); +kx*8192 selects panel
  const unsigned short* ardA[2];
#pragma unroll
  for (int h = 0; h < 2; ++h)
    ardA[h] = As + (moff + lm) * 64 + ((((h << 2) + g4) + moff + lm) & 7) * 8;
  // B reader bases per (kx,h): row = noffp + lm + kx (+16j)
  const unsigned short* ardB[3][2];
#pragma unroll
  for (int kx = 0; kx < 3; ++kx) {
    const int rb = noffp + lm + kx;
#pragma unroll
    for (int h = 0; h < 2; ++h)
      ardB[kx][h] = Bs + rb * 64 + ((((h << 2) + g4) + rb) & 7) * 8;
  }

  f32x4 acc[4][4];
#pragma unroll
  for (int i = 0; i < 4; ++i)
#pragma unroll
    for (int j = 0; j < 4; ++j) acc[i][j] = (f32x4){0.f, 0.f, 0.f, 0.f};

#pragma unroll 1
  for (int ky = 0; ky < 3; ++ky) {
    const unsigned short* Bp0 = xpad + bx + (size_t)((y0 + ky) * 66 + srow) * 512 + scol;
#pragma unroll 1
    for (int kb = 0; kb < 8; ++kb) {
      const int kcol = kb << 6;
      // stage 3 A tap-panels
#pragma unroll
      for (int kx = 0; kx < 3; ++kx) {
        const unsigned short* Ap = A0 + ((ky * 3 + kx) << 9) + kcol;
#pragma unroll
        for (int g = 0; g < 4; ++g)
          gload_lds16(Ap + g * (32 * 4608), As + ((kx << 13) + (((g << 8) + tid) << 3)));
      }
      // stage B halo strip: 132 rows (linear: pixel offset = (y0+ky)*66 + hr)
      const unsigned short* Bp = Bp0 + kcol;
#pragma unroll
      for (int g = 0; g < 4; ++g)
        gload_lds16(Bp + g * (32 * 512), Bs + (((g << 8) + tid) << 3));
      if (tid < 32) gload_lds16(Bp + 128 * 512, Bs + 8192 + tid * 8);
      __syncthreads();
#pragma unroll
      for (int kx = 0; kx < 3; ++kx) {
#pragma unroll
        for (int h = 0; h < 2; ++h) {
          bf16x8 af[4], bf[4];
          const unsigned short* pa = ardA[h] + (kx << 13);
          const unsigned short* pb = ardB[kx][h];
#pragma unroll
          for (int i = 0; i < 4; ++i) af[i] = *(const bf16x8*)(pa + (i << 10));
#pragma unroll
          for (int j = 0; j < 4; ++j) bf[j] = *(const bf16x8*)(pb + (j << 10));
#pragma unroll
          for (int i = 0; i < 4; ++i)
#pragma unroll
            for (int j = 0; j < 4; ++j)
              acc[i][j] = __builtin_amdgcn_mfma_f32_16x16x32_bf16(af[i], bf[j], acc[i][j], 0, 0, 0);
        }
      }
      __syncthreads();
    }
  }

  // epilogue: D layout col=lane&15 (pixel), row=(lane>>4)*4+reg (o); apply D[b][o]
  const float* dB = dmod + (b << 9) + m0 + moff;
  float* op = out + (size_t)((b << 9) + m0 + moff) * 4096 + n0 + noff;
#pragma unroll
  for (int i = 0; i < 4; ++i) {
#pragma unroll
    for (int r = 0; r < 4; ++r) {
      const int m = i * 16 + (g4 << 2) + r;
      const float dm = dB[m];
#pragma unroll
      for (int j = 0; j < 4; ++j)
        op[(size_t)m * 4096 + (j << 4) + lm] = acc[i][j][r] * dm;
    }
  }
}

extern "C" void kernel_launch(void* const* d_in, const int* in_sizes, int n_in,
                              void* d_out, int out_size, void* d_ws, size_t ws_size,
                              hipStream_t stream) {
  const float* x    = (const float*)d_in[0];   // (8,512,64,64)
  const float* w    = (const float*)d_in[1];   // (8,512)
  const float* bw   = (const float*)d_in[2];   // (1,512,512,3,3)
  const float* modw = (const float*)d_in[3];   // (512,512)
  const float* modb = (const float*)d_in[4];   // (512,)
  float* out = (float*)d_out;                  // (8,512,64,64) fp32
  char* ws = (char*)d_ws;

  float* s_buf = (float*)(ws);                              // 16 KB
  float* d_buf = (float*)(ws + 16384);                      // 16 KB
  unsigned short* awT  = (unsigned short*)(ws + 32768);     // 4,718,592 B
  unsigned short* xpad = (unsigned short*)(ws + 4751360);   // 35,684,352 B

  (void)in_sizes; (void)n_in; (void)out_size; (void)ws_size;

  k_style<<<64,   256, 0, stream>>>(w, modw, modb, s_buf);
  k_mid  <<<3104, 256, 0, stream>>>(bw, s_buf, awT, d_buf, x, xpad);
  k_conv <<<dim3(32, 4, 8), 256, 0, stream>>>(awT, xpad, d_buf, out);
}

// Round 11
// 265.067 us; speedup vs baseline: 1.5698x; 1.0048x over previous
//
#include <hip/hip_runtime.h>
#include <stdint.h>

// ModulatedConv2d: B=8, C=512, O=512, K=3, WDIM=512, H=W=64
// Round-15: k_conv flat-K 72-step schedule on the R7-verified 256x256 geometry.
//   Key insight: consecutive kx steps reuse the same B strip, so per-step
//   staging drops to ONE 32 KB A panel (+33 KB B every 3rd step), double-
//   buffered in 130 KB LDS (fits 160K) at 512 thr / 8 waves / 2 waves-SIMD.
//   2-phase: stageA(next) [+stageB at triple boundary] -> 64 MFMA/wave -> barrier.
//   Per-CU poles: MFMA 2483 cyc vs delivery ~780 cyc (hidden). All addressing
//   (swizzle, reader offsets, epilogue) verbatim from R7 (harness-verified).
//   dur x MfmaUtil == ~70 us across all rounds -> only MfmaUtil matters.

#define MOD_SCALE  0.044194173824159216f   // 1/sqrt(512)
#define CONV_SCALE 0.014731391274719739f   // 1/sqrt(4608)

typedef __attribute__((ext_vector_type(4))) float f32x4;
typedef __attribute__((ext_vector_type(8))) short bf16x8;

__device__ inline unsigned short f2bf(float f) {   // round-to-nearest-even
  uint32_t u = __float_as_uint(f);
  uint32_t r = (u + 0x7fffu + ((u >> 16) & 1u)) >> 16;
  return (unsigned short)r;
}

__device__ inline void gload_lds16(const void* g, void* l) {
  __builtin_amdgcn_global_load_lds(
      (const __attribute__((address_space(1))) void*)g,
      (__attribute__((address_space(3))) void*)l, 16, 0, 0);
}

// ---------- style: s[b][c] = w[b].modw[c]*MOD_SCALE + modb[c] + 1 ----------
__global__ __launch_bounds__(256) void k_style(const float* __restrict__ w,
                                               const float* __restrict__ modw,
                                               const float* __restrict__ modb,
                                               float* __restrict__ s_out) {
  __shared__ float red[256];
  const int tid = threadIdx.x;
  const int sb = blockIdx.x;
  const int cb = sb & 7, b = sb >> 3;
  const int cl = tid >> 2, qq = tid & 3;
  const int c = (cb << 6) + cl;
  const float4* wd = (const float4*)(w + (b << 9) + (qq << 7));
  const float4* md = (const float4*)(modw + ((size_t)c << 9) + (qq << 7));
  float acc = 0.f;
#pragma unroll
  for (int i = 0; i < 32; ++i) {
    float4 a = wd[i], m = md[i];
    acc += a.x * m.x + a.y * m.y + a.z * m.z + a.w * m.w;
  }
  red[tid] = acc;
  __syncthreads();
  if (tid < 64) {
    float v = red[tid * 4] + red[tid * 4 + 1] + red[tid * 4 + 2] + red[tid * 4 + 3];
    int cc = (cb << 6) + tid;
    s_out[(b << 9) + cc] = v * MOD_SCALE + modb[cc] + 1.0f;
  }
}

// ---------- merged mid-stage: fwd (blk<512) | xpose (<1024) | border (<3104) ----
__global__ __launch_bounds__(256) void k_mid(const float* __restrict__ bw,
                                             const float* __restrict__ s,
                                             unsigned short* __restrict__ awT,
                                             float* __restrict__ d_out,
                                             const float* __restrict__ x,
                                             unsigned short* __restrict__ xp) {
  __shared__ uint32_t tb[64 * 260];   // 66,560 B (fwd branch reuses as floats)
  const int blk = blockIdx.x;
  const int tid = threadIdx.x;

  if (blk < 512) {
    // ---------------- fwd: one block per o ----------------
    float* lw  = (float*)tb;          // 4608 floats
    float* ls  = lw + 4608;           // 4096 floats
    float* red = ls + 4096;           // 32 floats
    const int o = blk;
    {
      const float4* src = (const float4*)(bw + (size_t)o * 4608);
      float4* dst = (float4*)lw;
#pragma unroll
      for (int i = 0; i < 4; ++i) dst[tid + (i << 8)] = src[tid + (i << 8)];
      if (tid < 128) dst[tid + 1024] = src[tid + 1024];
    }
    {
      const float4* src = (const float4*)s;
      float4* dst = (float4*)ls;
#pragma unroll
      for (int i = 0; i < 4; ++i) dst[tid + (i << 8)] = src[tid + (i << 8)];
    }
    __syncthreads();
    const int c0 = tid << 1;
    const int base = c0 * 9;
    float wq0 = 0.f, wq1 = 0.f;
#pragma unroll
    for (int j = 0; j < 9; ++j) {
      float a = lw[base + j];      wq0 += a * a;
      float b2 = lw[base + 9 + j]; wq1 += b2 * b2;
    }
    const int lane = tid & 63, wv = tid >> 6;
#pragma unroll
    for (int b = 0; b < 8; ++b) {
      float s0 = ls[(b << 9) + c0], s1 = ls[(b << 9) + c0 + 1];
      float v = wq0 * s0 * s0 + wq1 * s1 * s1;
#pragma unroll
      for (int off = 32; off > 0; off >>= 1) v += __shfl_down(v, off, 64);
      if (lane == 0) red[(b << 2) + wv] = v;
    }
    __syncthreads();
    if (tid < 8) {
      float a = red[tid << 2] + red[(tid << 2) + 1] + red[(tid << 2) + 2] + red[(tid << 2) + 3];
      d_out[(tid << 9) + o] = rsqrtf(a * (1.0f / 4608.0f)) * CONV_SCALE;
    }
    uint32_t* dst = (uint32_t*)(awT + (size_t)o * 4608);
#pragma unroll
    for (int j = 0; j < 9; ++j)
      dst[(j << 8) + tid] = (uint32_t)f2bf(lw[base + j]) |
                            ((uint32_t)f2bf(lw[base + 9 + j]) << 16);
  } else if (blk < 1024) {
    // ---------------- xpose: one block per (b, y) ----------------
    const int q = blk - 512;
    const int b = q >> 6, y = q & 63;
    const int px4 = tid & 15;
    const int cp  = tid >> 4;
    const float* xb = x + (size_t)(b << 9) * 4096 + (y << 6) + (px4 << 2);
    const float* sb = s + (b << 9);
#pragma unroll
    for (int it = 0; it < 16; ++it) {
      const int cpair = cp + (it << 4);
      const int c0 = cpair << 1;
      const float4 a0 = *(const float4*)(xb + (size_t)c0 * 4096);
      const float4 a1 = *(const float4*)(xb + (size_t)(c0 + 1) * 4096);
      const float s0 = sb[c0], s1 = sb[c0 + 1];
      const int pxb = px4 << 2;
      tb[(pxb + 0) * 260 + cpair] = (uint32_t)f2bf(a0.x * s0) | ((uint32_t)f2bf(a1.x * s1) << 16);
      tb[(pxb + 1) * 260 + cpair] = (uint32_t)f2bf(a0.y * s0) | ((uint32_t)f2bf(a1.y * s1) << 16);
      tb[(pxb + 2) * 260 + cpair] = (uint32_t)f2bf(a0.z * s0) | ((uint32_t)f2bf(a1.z * s1) << 16);
      tb[(pxb + 3) * 260 + cpair] = (uint32_t)f2bf(a0.w * s0) | ((uint32_t)f2bf(a1.w * s1) << 16);
    }
    __syncthreads();
    const int wv = tid >> 6, l = tid & 63;
    uint32_t* xpw = (uint32_t*)xp;
#pragma unroll
    for (int it = 0; it < 16; ++it) {
      const int px = (wv << 4) + it;
      const uint4 v = *(const uint4*)(tb + px * 260 + (l << 2));
      const size_t base = ((size_t)b * 4356 + (size_t)(y + 1) * 66 + (px + 1)) << 8;
      ((uint4*)(xpw + base))[l] = v;
    }
  } else {
    // ---------------- border: zero the 1-px frame ----------------
    const int q = blk - 1024;
    const int b = q / 260, p = q - b * 260;
    int py, px;
    if (p < 66)       { py = 0;       px = p; }
    else if (p < 132) { py = 65;      px = p - 66; }
    else if (p < 196) { py = p - 131; px = 0; }
    else              { py = p - 195; px = 65; }
    uint32_t* dst = (uint32_t*)(xp + ((size_t)b * 4356 + py * 66 + px) * 512);
    dst[tid] = 0u;
  }
}

// ---------- main conv: 256x256 block, 512 thr, flat-K 72 steps, dbuf ----------
// LDS: As[2] 256x64 (2x32 KB) + Bs[2] 264-px strip x 64 (2x33 KB) = 130 KB.
// Per step: stageA(next panel, 32 KB) [+stageB(33 KB) at triple boundary]
//   -> 64 MFMA/wave on current buffers -> one barrier. B reused across kx.
__global__ __launch_bounds__(512, 1) void k_conv(const unsigned short* __restrict__ awT,
                                                 const unsigned short* __restrict__ xpad,
                                                 const float* __restrict__ dmod,
                                                 float* __restrict__ out) {
  __shared__ alignas(16) unsigned short As[2][16384];  // 2 x 32 KB
  __shared__ alignas(16) unsigned short Bs[2][16896];  // 2 x 33 KB
  const int tid = threadIdx.x;

  const int nI = blockIdx.x;           // 0..15
  const int m0 = blockIdx.y << 8;      // 0 or 256
  const int b  = blockIdx.z;
  const int n0 = nI << 8;
  const int y0 = nI << 2;              // 4 output rows per tile

  // staging mapping (R7-verified): row = g*64 + (t>>3), swizzled chunk
  const int srow = tid >> 3;                         // 0..63
  const int schk = ((tid & 7) - (srow & 7)) & 7;     // logical chunk to fetch
  const int scol = schk << 3;

  const unsigned short* A0 = awT + (size_t)(m0 + srow) * 4608 + scol;
  const size_t bx = (size_t)b * (66 * 66 * 512);
  const unsigned short* B0 = xpad + bx + (size_t)(y0 * 66 + srow) * 512 + scol;

  const int lane = tid & 63;
  const int wv   = tid >> 6;           // 0..7
  const int moff = (wv >> 1) << 6;     // 0,64,128,192
  const int lm   = lane & 15;
  const int g4   = lane >> 4;

  // A reader offsets (R1/R7-verified 8-chunk swizzle, 64-wide rows)
  const int arow = moff + lm;
  int aoff[2];
#pragma unroll
  for (int h = 0; h < 2; ++h)
    aoff[h] = arow * 64 + ((((h << 2) + g4) + arow) & 7) * 8;
  // B reader offsets [kx][jr][h] (R7-verified): row = ((wv&1)*2+jr)*66 + lm + kx
  int boff[3][2][2];
#pragma unroll
  for (int kx = 0; kx < 3; ++kx)
#pragma unroll
    for (int jr = 0; jr < 2; ++jr) {
      const int rb = ((wv & 1) * 2 + jr) * 66 + lm + kx;
#pragma unroll
      for (int h = 0; h < 2; ++h)
        boff[kx][jr][h] = rb * 64 + ((((h << 2) + g4) + rb) & 7) * 8;
    }

  f32x4 acc[4][8];
#pragma unroll
  for (int i = 0; i < 4; ++i)
#pragma unroll
    for (int j = 0; j < 8; ++j) acc[i][j] = (f32x4){0.f, 0.f, 0.f, 0.f};

  // stage one 32 KB A panel (tap (ky,kx), c-slice kb) into As[buf]
  auto stageA = [&](int buf, int ky, int kx, int kb) {
    const unsigned short* Ap = A0 + (((ky * 3 + kx) << 9) + (kb << 6));
#pragma unroll
    for (int g = 0; g < 4; ++g)
      gload_lds16(Ap + (size_t)(g << 6) * 4608, &As[buf][(g << 12) + (tid << 3)]);
  };
  // stage one 33 KB B strip (row family ky, c-slice kb) into Bs[buf]
  auto stageB = [&](int buf, int ky, int kb) {
    const unsigned short* Bp = B0 + (size_t)(ky * 66) * 512 + (kb << 6);
#pragma unroll
    for (int g = 0; g < 4; ++g)
      gload_lds16(Bp + (size_t)(g << 6) * 512, &Bs[buf][(g << 12) + (tid << 3)]);
    if (tid < 64) gload_lds16(Bp + (size_t)256 * 512, &Bs[buf][16384 + (tid << 3)]);
  };
  // one step's MFMA: 64 per wave on As[ab], Bs[bb], tap column kx
  auto mstep = [&](int ab, int bb, int kx) {
    __builtin_amdgcn_s_setprio(1);
#pragma unroll
    for (int h = 0; h < 2; ++h) {
      bf16x8 af[4], bfr[8];
      const unsigned short* pa = As[ab] + aoff[h];
#pragma unroll
      for (int i = 0; i < 4; ++i) af[i] = *(const bf16x8*)(pa + (i << 10));
#pragma unroll
      for (int j = 0; j < 8; ++j)
        bfr[j] = *(const bf16x8*)(Bs[bb] + boff[kx][j >> 2][h] + ((j & 3) << 10));
#pragma unroll
      for (int i = 0; i < 4; ++i)
#pragma unroll
        for (int j = 0; j < 8; ++j)
          acc[i][j] = __builtin_amdgcn_mfma_f32_16x16x32_bf16(af[i], bfr[j], acc[i][j], 0, 0, 0);
    }
    __builtin_amdgcn_s_setprio(0);
  };

  // prologue: first A panel + first B strip
  stageA(0, 0, 0, 0);
  stageB(0, 0, 0);
  __syncthreads();

  int ab = 0, bb = 0;
#pragma unroll 1
  for (int ky = 0; ky < 3; ++ky) {
#pragma unroll 1
    for (int kb = 0; kb < 8; ++kb) {
      // step kx=0: prefetch A(kx=1)
      stageA(ab ^ 1, ky, 1, kb);
      mstep(ab, bb, 0);
      __syncthreads();
      ab ^= 1;
      // step kx=1: prefetch A(kx=2)
      stageA(ab ^ 1, ky, 2, kb);
      mstep(ab, bb, 1);
      __syncthreads();
      ab ^= 1;
      // step kx=2: prefetch next triple's A(kx=0) + B strip
      const int nky = (kb == 7) ? ky + 1 : ky;
      const int nkb = (kb == 7) ? 0 : kb + 1;
      if (!(ky == 2 && kb == 7)) {
        stageA(ab ^ 1, nky, 0, nkb);
        stageB(bb ^ 1, nky, nkb);
      }
      mstep(ab, bb, 2);
      __syncthreads();
      ab ^= 1;
      bb ^= 1;
    }
  }

  // epilogue (R7-verified): D col=lane&15 (pixel), row=(lane>>4)*4+reg (o)
  const float* dB = dmod + (b << 9) + m0 + moff;
  float* op = out + (size_t)((b << 9) + m0 + moff) * 4096 + n0 + ((wv & 1) << 7);
#pragma unroll
  for (int i = 0; i < 4; ++i) {
#pragma unroll
    for (int r = 0; r < 4; ++r) {
      const int m = i * 16 + (g4 << 2) + r;
      const float dm = dB[m];
#pragma unroll
      for (int j = 0; j < 8; ++j)
        op[(size_t)m * 4096 + (j << 4) + lm] = acc[i][j][r] * dm;
    }
  }
}

extern "C" void kernel_launch(void* const* d_in, const int* in_sizes, int n_in,
                              void* d_out, int out_size, void* d_ws, size_t ws_size,
                              hipStream_t stream) {
  const float* x    = (const float*)d_in[0];   // (8,512,64,64)
  const float* w    = (const float*)d_in[1];   // (8,512)
  const float* bw   = (const float*)d_in[2];   // (1,512,512,3,3)
  const float* modw = (const float*)d_in[3];   // (512,512)
  const float* modb = (const float*)d_in[4];   // (512,)
  float* out = (float*)d_out;                  // (8,512,64,64) fp32
  char* ws = (char*)d_ws;

  float* s_buf = (float*)(ws);                              // 16 KB
  float* d_buf = (float*)(ws + 16384);                      // 16 KB
  unsigned short* awT  = (unsigned short*)(ws + 32768);     // 4,718,592 B
  unsigned short* xpad = (unsigned short*)(ws + 4751360);   // 35,684,352 B

  (void)in_sizes; (void)n_in; (void)out_size; (void)ws_size;

  k_style<<<64,   256, 0, stream>>>(w, modw, modb, s_buf);
  k_mid  <<<3104, 256, 0, stream>>>(bw, s_buf, awT, d_buf, x, xpad);
  k_conv <<<dim3(16, 2, 8), 512, 0, stream>>>(awT, xpad, d_buf, out);
}